// Round 1
// baseline (2170.984 us; speedup 1.0000x reference)
//
#include <hip/hip_runtime.h>

static constexpr int B_   = 8;
static constexpr int C_   = 256;
static constexpr int CQK_ = 32;
static constexpr int N_   = 4096;   // 64*64

// ---------------------------------------------------------------------------
// Projection: x[b,:,n-tile] -> Q[b,n,32], K[b,n,32], V[b,n,256]
// grid = B * (N/64) = 512 blocks, 256 threads
// ---------------------------------------------------------------------------
__global__ __launch_bounds__(256) void proj_kernel(
    const float* __restrict__ x,
    const float* __restrict__ Wq, const float* __restrict__ bq,
    const float* __restrict__ Wk, const float* __restrict__ bk,
    const float* __restrict__ Wv, const float* __restrict__ bv,
    float* __restrict__ Qws, float* __restrict__ Kws, float* __restrict__ Vws)
{
    __shared__ float xs[64][260];    // [n][c], pad 260 (stride 1040B, 16B-aligned)
    const int b  = blockIdx.x >> 6;
    const int n0 = (blockIdx.x & 63) << 6;
    const int t  = threadIdx.x;
    const float* xb = x + (size_t)b * C_ * N_;

    // stage x[b, c, n0:n0+64] -> xs[n][c]  (coalesced global reads)
    {
        const int c0 = t >> 4;
        const int n4 = (t & 15) << 2;
        #pragma unroll
        for (int i = 0; i < 16; ++i) {
            const int cc = i * 16 + c0;
            float4 g = *(const float4*)(xb + (size_t)cc * N_ + n0 + n4);
            xs[n4 + 0][cc] = g.x;
            xs[n4 + 1][cc] = g.y;
            xs[n4 + 2][cc] = g.z;
            xs[n4 + 3][cc] = g.w;
        }
    }
    __syncthreads();

    // V: each thread -> 8 output channels x 8 positions
    {
        const int og = (t & 31) * 8;
        const int ng = (t >> 5) * 8;
        float acc[8][8];
        #pragma unroll
        for (int k = 0; k < 8; ++k)
            #pragma unroll
            for (int j = 0; j < 8; ++j) acc[k][j] = 0.f;

        for (int c4 = 0; c4 < 64; ++c4) {
            float4 w[8];
            #pragma unroll
            for (int k = 0; k < 8; ++k)
                w[k] = *(const float4*)(Wv + (size_t)(og + k) * C_ + c4 * 4);
            #pragma unroll
            for (int j = 0; j < 8; ++j) {
                float4 xv = *(const float4*)(&xs[ng + j][c4 * 4]);
                #pragma unroll
                for (int k = 0; k < 8; ++k)
                    acc[k][j] += w[k].x * xv.x + w[k].y * xv.y
                               + w[k].z * xv.z + w[k].w * xv.w;
            }
        }
        #pragma unroll
        for (int j = 0; j < 8; ++j)
            #pragma unroll
            for (int k = 0; k < 8; ++k)
                Vws[((size_t)b * N_ + n0 + ng + j) * C_ + og + k] = acc[k][j] + bv[og + k];
    }

    // Q/K: each thread -> 8 output channels x 2 positions (64 qk channels total)
    {
        const int o  = (t & 7) * 8;        // 0..56
        const int ng = (t >> 3) * 2;
        const bool isQ = (o < 32);
        const float* Wrow = isQ ? (Wq + (size_t)o * C_) : (Wk + (size_t)(o - 32) * C_);
        const float* brow = isQ ? (bq + o) : (bk + (o - 32));
        float* dst  = isQ ? Qws : Kws;
        const int oc = isQ ? o : (o - 32);

        float acc[8][2];
        #pragma unroll
        for (int k = 0; k < 8; ++k) { acc[k][0] = 0.f; acc[k][1] = 0.f; }

        for (int c4 = 0; c4 < 64; ++c4) {
            float4 w[8];
            #pragma unroll
            for (int k = 0; k < 8; ++k)
                w[k] = *(const float4*)(Wrow + (size_t)k * C_ + c4 * 4);
            #pragma unroll
            for (int j = 0; j < 2; ++j) {
                float4 xv = *(const float4*)(&xs[ng + j][c4 * 4]);
                #pragma unroll
                for (int k = 0; k < 8; ++k)
                    acc[k][j] += w[k].x * xv.x + w[k].y * xv.y
                               + w[k].z * xv.z + w[k].w * xv.w;
            }
        }
        #pragma unroll
        for (int j = 0; j < 2; ++j)
            #pragma unroll
            for (int k = 0; k < 8; ++k)
                dst[((size_t)b * N_ + n0 + ng + j) * CQK_ + oc + k] = acc[k][j] + brow[k];
    }
}

// ---------------------------------------------------------------------------
// Softmax row stats: max and 1/sum over keys for every (b, n)
// grid = B * (N/64) = 512 blocks, 256 threads
// thread: query = t&63, key-partition = t>>6 (1024 keys each)
// ---------------------------------------------------------------------------
__global__ __launch_bounds__(256) void stats_kernel(
    const float* __restrict__ Qws, const float* __restrict__ Kws,
    float* __restrict__ MX, float* __restrict__ ISUM)
{
    __shared__ float sm[4][64];
    __shared__ float ss[4][64];
    const int t    = threadIdx.x;
    const int q    = t & 63;
    const int part = t >> 6;
    const int b    = blockIdx.x >> 6;
    const int n0   = (blockIdx.x & 63) << 6;

    const float* qp = Qws + ((size_t)b * N_ + n0 + q) * CQK_;
    float4 qv[8];
    #pragma unroll
    for (int i = 0; i < 8; ++i) qv[i] = *(const float4*)(qp + i * 4);

    const float* kb = Kws + (size_t)b * N_ * CQK_ + (size_t)part * 1024 * CQK_;
    float mx = -3.0e38f, sum = 0.f;
    for (int m = 0; m < 1024; ++m) {
        const float* kp = kb + (size_t)m * CQK_;
        float s = 0.f;
        #pragma unroll
        for (int i = 0; i < 8; ++i) {
            float4 kv = *(const float4*)(kp + i * 4);
            s += qv[i].x * kv.x + qv[i].y * kv.y + qv[i].z * kv.z + qv[i].w * kv.w;
        }
        float nmx = fmaxf(mx, s);
        sum = sum * __expf(mx - nmx) + __expf(s - nmx);
        mx = nmx;
    }
    sm[part][q] = mx;
    ss[part][q] = sum;
    __syncthreads();
    if (t < 64) {
        float m0 = sm[0][t], m1 = sm[1][t], m2 = sm[2][t], m3 = sm[3][t];
        float gm = fmaxf(fmaxf(m0, m1), fmaxf(m2, m3));
        float s  = ss[0][t] * __expf(m0 - gm) + ss[1][t] * __expf(m1 - gm)
                 + ss[2][t] * __expf(m2 - gm) + ss[3][t] * __expf(m3 - gm);
        MX[b * N_ + n0 + t]   = gm;
        ISUM[b * N_ + n0 + t] = 1.0f / s;
    }
}

// ---------------------------------------------------------------------------
// Attention + residual: out[b,c,n] = gamma * sum_m P[n,m] V[m,c] + x[b,c,n]
// grid = 512 blocks (b = blk&7 -> XCD-affine), 256 threads, 64-query tile
// ---------------------------------------------------------------------------
__global__ __launch_bounds__(256) void attn_kernel(
    const float* __restrict__ x,
    const float* __restrict__ Qws, const float* __restrict__ Kws,
    const float* __restrict__ Vws,
    const float* __restrict__ MX, const float* __restrict__ ISUM,
    const float* __restrict__ gamma,
    float* __restrict__ out)
{
    __shared__ float p_lds[64][68];   // [q][m], stride 272B (16B-aligned)
    const int b  = blockIdx.x & 7;            // all tiles of a batch on one XCD
    const int n0 = (blockIdx.x >> 3) << 6;
    const int t  = threadIdx.x;

    // phase-A identity: one query per lane, 16 keys per wave-column
    const int qa = t & 63;
    const int mg = (t >> 6) << 4;             // 0,16,32,48
    float4 qv[8];
    const float* qp = Qws + ((size_t)b * N_ + n0 + qa) * CQK_;
    #pragma unroll
    for (int i = 0; i < 8; ++i) qv[i] = *(const float4*)(qp + i * 4);
    const float mx   = MX  [b * N_ + n0 + qa];
    const float isum = ISUM[b * N_ + n0 + qa];

    // phase-B identity: 8 channels x 8 queries per thread
    const int cq  = (t & 31) << 3;
    const int qb0 = (t >> 5) << 3;
    float acc[8][8];                          // [query][channel]
    #pragma unroll
    for (int i = 0; i < 8; ++i)
        #pragma unroll
        for (int j = 0; j < 8; ++j) acc[i][j] = 0.f;

    const float* kb = Kws + (size_t)b * N_ * CQK_;
    const float* vb = Vws + (size_t)b * N_ * C_;

    for (int m0 = 0; m0 < N_; m0 += 64) {
        // ---- phase A: P chunk [64 q][64 m] ----
        #pragma unroll
        for (int j = 0; j < 16; ++j) {
            const float* kp = kb + (size_t)(m0 + mg + j) * CQK_;
            float s = 0.f;
            #pragma unroll
            for (int i = 0; i < 8; ++i) {
                float4 kv = *(const float4*)(kp + i * 4);
                s += qv[i].x * kv.x + qv[i].y * kv.y + qv[i].z * kv.z + qv[i].w * kv.w;
            }
            p_lds[qa][mg + j] = __expf(s - mx) * isum;
        }
        __syncthreads();

        // ---- phase B: acc += P * V ----
        for (int mm = 0; mm < 64; mm += 4) {
            float4 vv[8];                     // [m j][channel-half h] -> vv[j*2+h]
            #pragma unroll
            for (int j = 0; j < 4; ++j) {
                const float* vp = vb + (size_t)(m0 + mm + j) * C_ + cq;
                vv[j * 2 + 0] = *(const float4*)(vp);
                vv[j * 2 + 1] = *(const float4*)(vp + 4);
            }
            #pragma unroll
            for (int qi = 0; qi < 8; ++qi) {
                float4 pq = *(const float4*)(&p_lds[qb0 + qi][mm]);
                acc[qi][0] += pq.x*vv[0].x + pq.y*vv[2].x + pq.z*vv[4].x + pq.w*vv[6].x;
                acc[qi][1] += pq.x*vv[0].y + pq.y*vv[2].y + pq.z*vv[4].y + pq.w*vv[6].y;
                acc[qi][2] += pq.x*vv[0].z + pq.y*vv[2].z + pq.z*vv[4].z + pq.w*vv[6].z;
                acc[qi][3] += pq.x*vv[0].w + pq.y*vv[2].w + pq.z*vv[4].w + pq.w*vv[6].w;
                acc[qi][4] += pq.x*vv[1].x + pq.y*vv[3].x + pq.z*vv[5].x + pq.w*vv[7].x;
                acc[qi][5] += pq.x*vv[1].y + pq.y*vv[3].y + pq.z*vv[5].y + pq.w*vv[7].y;
                acc[qi][6] += pq.x*vv[1].z + pq.y*vv[3].z + pq.z*vv[5].z + pq.w*vv[7].z;
                acc[qi][7] += pq.x*vv[1].w + pq.y*vv[3].w + pq.z*vv[5].w + pq.w*vv[7].w;
            }
        }
        __syncthreads();
    }

    // ---- epilogue: out = gamma*acc + x ----
    const float g = gamma[0];
    const float* xb = x   + (size_t)b * C_ * N_;
    float*       ob = out + (size_t)b * C_ * N_;
    #pragma unroll
    for (int k = 0; k < 8; ++k) {
        const int c = cq + k;
        #pragma unroll
        for (int qi = 0; qi < 8; qi += 4) {
            const int n = n0 + qb0 + qi;
            float4 xv = *(const float4*)(xb + (size_t)c * N_ + n);
            float4 o;
            o.x = g * acc[qi + 0][k] + xv.x;
            o.y = g * acc[qi + 1][k] + xv.y;
            o.z = g * acc[qi + 2][k] + xv.z;
            o.w = g * acc[qi + 3][k] + xv.w;
            *(float4*)(ob + (size_t)c * N_ + n) = o;
        }
    }
}

// ---------------------------------------------------------------------------
extern "C" void kernel_launch(void* const* d_in, const int* in_sizes, int n_in,
                              void* d_out, int out_size, void* d_ws, size_t ws_size,
                              hipStream_t stream)
{
    const float* x     = (const float*)d_in[0];
    const float* Wq    = (const float*)d_in[1];
    const float* bq    = (const float*)d_in[2];
    const float* Wk    = (const float*)d_in[3];
    const float* bk    = (const float*)d_in[4];
    const float* Wv    = (const float*)d_in[5];
    const float* bv    = (const float*)d_in[6];
    const float* gamma = (const float*)d_in[7];
    float* out = (float*)d_out;

    float* ws  = (float*)d_ws;
    float* Qws = ws;                                   // B*N*32
    float* Kws = Qws + (size_t)B_ * N_ * CQK_;         // B*N*32
    float* Vws = Kws + (size_t)B_ * N_ * CQK_;         // B*N*256
    float* MX  = Vws + (size_t)B_ * N_ * C_;           // B*N
    float* ISUM = MX + (size_t)B_ * N_;                // B*N

    proj_kernel <<<B_ * (N_ / 64), 256, 0, stream>>>(x, Wq, bq, Wk, bk, Wv, bv,
                                                     Qws, Kws, Vws);
    stats_kernel<<<B_ * (N_ / 64), 256, 0, stream>>>(Qws, Kws, MX, ISUM);
    attn_kernel <<<B_ * (N_ / 64), 256, 0, stream>>>(x, Qws, Kws, Vws, MX, ISUM,
                                                     gamma, out);
}

// Round 2
// 355.942 us; speedup vs baseline: 6.0993x; 6.0993x over previous
//
#include <hip/hip_runtime.h>

static constexpr int B_   = 8;
static constexpr int C_   = 256;
static constexpr int CQK_ = 32;
static constexpr int N_   = 4096;   // 64*64

typedef __attribute__((ext_vector_type(4))) float f32x4;
typedef __attribute__((ext_vector_type(8))) short short8;
typedef __attribute__((ext_vector_type(2))) unsigned int u32x2;
typedef unsigned short ushort_t;

// round-to-nearest-even fp32 -> bf16 (bit twiddle; no API dependence)
__device__ inline unsigned short f2bf(float f) {
    unsigned u = __float_as_uint(f);
    return (unsigned short)((u + 0x7FFFu + ((u >> 16) & 1u)) >> 16);
}
__device__ inline unsigned packbf(float lo, float hi) {
    return (unsigned)f2bf(lo) | ((unsigned)f2bf(hi) << 16);
}

// swizzle of the byte offset within a 64-row V/P chunk row, as fn of row m:
// flips byte bits 4..6 -> conflict-free tr-reads; involution; 16B-granule safe
__device__ inline int swzbits(int m) {
    return ((m & 3) << 5) | (((m >> 3) & 1) << 4);
}

template <int OFF>
__device__ inline u32x2 tr8(unsigned a) {
    u32x2 d;
    asm volatile("ds_read_b64_tr_b16 %0, %1 offset:%2"
                 : "=v"(d) : "v"(a), "i"(OFF));
    return d;
}

__device__ inline short8 mk8(u32x2 lo, u32x2 hi) {
    union { unsigned u[4]; short8 s; } v;
    v.u[0] = lo.x; v.u[1] = lo.y; v.u[2] = hi.x; v.u[3] = hi.y;
    return v.s;
}

// ---------------------------------------------------------------------------
// Projection: x[b,:,n-tile] -> Qb[b,n,32] bf16, Kb[b,n,32] bf16,
//             Vb[b,m,256] bf16 with per-row swizzled c-offset.
// grid = B * (N/64) = 512 blocks, 256 threads
// ---------------------------------------------------------------------------
__global__ __launch_bounds__(256) void proj_kernel(
    const float* __restrict__ x,
    const float* __restrict__ Wq, const float* __restrict__ bq,
    const float* __restrict__ Wk, const float* __restrict__ bk,
    const float* __restrict__ Wv, const float* __restrict__ bv,
    ushort_t* __restrict__ Qb, ushort_t* __restrict__ Kb, ushort_t* __restrict__ Vb)
{
    __shared__ float xs[64][260];
    const int b  = blockIdx.x >> 6;
    const int n0 = (blockIdx.x & 63) << 6;
    const int t  = threadIdx.x;
    const float* xb = x + (size_t)b * C_ * N_;

    // stage x[b, c, n0:n0+64] -> xs[n][c]
    {
        const int c0 = t >> 4;
        const int n4 = (t & 15) << 2;
        #pragma unroll
        for (int i = 0; i < 16; ++i) {
            const int cc = i * 16 + c0;
            float4 gv = *(const float4*)(xb + (size_t)cc * N_ + n0 + n4);
            xs[n4 + 0][cc] = gv.x;
            xs[n4 + 1][cc] = gv.y;
            xs[n4 + 2][cc] = gv.z;
            xs[n4 + 3][cc] = gv.w;
        }
    }
    __syncthreads();

    // V: 8 output channels x 8 positions per thread
    {
        const int og = (t & 31) * 8;
        const int ng = (t >> 5) * 8;
        float acc[8][8];
        #pragma unroll
        for (int k = 0; k < 8; ++k)
            #pragma unroll
            for (int j = 0; j < 8; ++j) acc[k][j] = 0.f;

        for (int c4 = 0; c4 < 64; ++c4) {
            float4 wv[8];
            #pragma unroll
            for (int k = 0; k < 8; ++k)
                wv[k] = *(const float4*)(Wv + (size_t)(og + k) * C_ + c4 * 4);
            #pragma unroll
            for (int j = 0; j < 8; ++j) {
                float4 xv = *(const float4*)(&xs[ng + j][c4 * 4]);
                #pragma unroll
                for (int k = 0; k < 8; ++k)
                    acc[k][j] += wv[k].x * xv.x + wv[k].y * xv.y
                               + wv[k].z * xv.z + wv[k].w * xv.w;
            }
        }
        float bvv[8];
        #pragma unroll
        for (int k = 0; k < 8; ++k) bvv[k] = bv[og + k];
        #pragma unroll
        for (int j = 0; j < 8; ++j) {
            const int m = ng + j;                 // row within 64-chunk
            unsigned pk0 = packbf(acc[0][j] + bvv[0], acc[1][j] + bvv[1]);
            unsigned pk1 = packbf(acc[2][j] + bvv[2], acc[3][j] + bvv[3]);
            unsigned pk2 = packbf(acc[4][j] + bvv[4], acc[5][j] + bvv[5]);
            unsigned pk3 = packbf(acc[6][j] + bvv[6], acc[7][j] + bvv[7]);
            uint4 pk; pk.x = pk0; pk.y = pk1; pk.z = pk2; pk.w = pk3;
            char* dst = (char*)Vb + (size_t)(b * N_ + n0 + m) * 512
                                  + ((og * 2) ^ swzbits(m));
            *(uint4*)dst = pk;
        }
    }

    // Q/K: 8 channels x 2 positions per thread
    {
        const int o  = (t & 7) * 8;
        const int ng = (t >> 3) * 2;
        const bool isQ = (o < 32);
        const float* Wrow = isQ ? (Wq + (size_t)o * C_) : (Wk + (size_t)(o - 32) * C_);
        const float* brow = isQ ? (bq + o) : (bk + (o - 32));
        ushort_t* dst = isQ ? Qb : Kb;
        const int oc = isQ ? o : (o - 32);

        float acc[8][2];
        #pragma unroll
        for (int k = 0; k < 8; ++k) { acc[k][0] = 0.f; acc[k][1] = 0.f; }

        for (int c4 = 0; c4 < 64; ++c4) {
            float4 wv[8];
            #pragma unroll
            for (int k = 0; k < 8; ++k)
                wv[k] = *(const float4*)(Wrow + (size_t)k * C_ + c4 * 4);
            #pragma unroll
            for (int j = 0; j < 2; ++j) {
                float4 xv = *(const float4*)(&xs[ng + j][c4 * 4]);
                #pragma unroll
                for (int k = 0; k < 8; ++k)
                    acc[k][j] += wv[k].x * xv.x + wv[k].y * xv.y
                               + wv[k].z * xv.z + wv[k].w * xv.w;
            }
        }
        #pragma unroll
        for (int j = 0; j < 2; ++j) {
            uint4 pk;
            pk.x = packbf(acc[0][j] + brow[0], acc[1][j] + brow[1]);
            pk.y = packbf(acc[2][j] + brow[2], acc[3][j] + brow[3]);
            pk.z = packbf(acc[4][j] + brow[4], acc[5][j] + brow[5]);
            pk.w = packbf(acc[6][j] + brow[6], acc[7][j] + brow[7]);
            *(uint4*)(dst + (size_t)(b * N_ + n0 + ng + j) * CQK_ + oc) = pk;
        }
    }
}

// ---------------------------------------------------------------------------
// Fused attention: S=QK^T (MFMA), P=exp(S) unnormalized, PV (MFMA via
// tr-reads), denominator accumulated inline, normalized in epilogue.
// grid = 512 (b = blk&7 XCD-affine), 256 threads (4 waves), 64-query tile
// ---------------------------------------------------------------------------
__global__ __launch_bounds__(256) void attn_kernel(
    const float* __restrict__ x,
    const ushort_t* __restrict__ Qb, const ushort_t* __restrict__ Kb,
    const ushort_t* __restrict__ Vb,
    const float* __restrict__ gamma, float* __restrict__ out)
{
    __shared__ __align__(16) unsigned char smem[32768 + 8192 + 256];
    unsigned char* Pl = smem + 32768;
    float* rsl = (float*)(smem + 32768 + 8192);

    typedef __attribute__((address_space(3))) unsigned char lds_byte;
    const unsigned sbase = (unsigned)(size_t)(lds_byte*)smem;

    const int b  = blockIdx.x & 7;
    const int n0 = (blockIdx.x >> 3) << 6;
    const int t  = threadIdx.x;
    const int l  = t & 63, w = t >> 6;
    const int li = l & 15, g = l >> 4;
    const int rr = li >> 2, ss = l & 3;
    const int hq = w & 1,  hc = w >> 1;
    const int swz_tr = (rr << 5) | ((g & 1) << 4);

    // Q fragment: A-frag rows q = n0+16w+li, k = 8g..8g+7
    short8 qf = *(const short8*)(Qb + (size_t)(b * N_ + n0 + 16 * w + li) * CQK_ + 8 * g);

    f32x4 acc[2][8];
    #pragma unroll
    for (int i = 0; i < 2; ++i)
        #pragma unroll
        for (int j = 0; j < 8; ++j) acc[i][j] = (f32x4){0.f, 0.f, 0.f, 0.f};
    float rs0 = 0.f, rs1 = 0.f, rs2 = 0.f, rs3 = 0.f;

    const ushort_t* Kbb = Kb + (size_t)(b * N_) * CQK_;
    const char* Vgb = (const char*)Vb + (size_t)(b * N_) * 512;
    const f32x4 zf = {0.f, 0.f, 0.f, 0.f};

    for (int m0 = 0; m0 < N_; m0 += 64) {
        // --- K fragments (global, L2-resident; issued before V stage) ---
        short8 kf[4];
        #pragma unroll
        for (int jm = 0; jm < 4; ++jm)
            kf[jm] = *(const short8*)(Kbb + (size_t)(m0 + 16 * jm + li) * CQK_ + 8 * g);

        // --- stage V chunk [64m x 256c] bf16 (32KB, swizzled layout) ---
        {
            const char* gsrc = Vgb + (size_t)m0 * 512 + w * 1024 + l * 16;
            #pragma unroll
            for (int i = 0; i < 8; ++i)
                __builtin_amdgcn_global_load_lds(
                    (const __attribute__((address_space(1))) unsigned int*)(gsrc + i * 4096),
                    (__attribute__((address_space(3))) unsigned int*)(smem + w * 1024 + i * 4096),
                    16, 0, 0);
        }

        // --- S = Q K^T, exp, rowsum, pack P^T into LDS ---
        #pragma unroll
        for (int jm = 0; jm < 4; ++jm) {
            f32x4 s = __builtin_amdgcn_mfma_f32_16x16x32_bf16(qf, kf[jm], zf, 0, 0, 0);
            float p0 = __expf(s[0]), p1 = __expf(s[1]);
            float p2 = __expf(s[2]), p3 = __expf(s[3]);
            rs0 += p0; rs1 += p1; rs2 += p2; rs3 += p3;
            const int m = 16 * jm + li;          // P^T row
            u32x2 pu; pu.x = packbf(p0, p1); pu.y = packbf(p2, p3);
            *(u32x2*)(Pl + m * 128 + ((32 * w + 8 * g) ^ swzbits(m))) = pu;
        }
        __syncthreads();   // P^T visible, V stage drained (vmcnt 0 + lgkmcnt 0)

        // --- PV: acc[q 32][c 128] += P[q, m64] * V[m64, c] ---
        #pragma unroll
        for (int kb = 0; kb < 2; ++kb) {
            u32x2 pa[2][2], vbf[8][2];
            #pragma unroll
            for (int jq = 0; jq < 2; ++jq) {
                unsigned a = sbase + 32768u
                           + (32 * kb + 8 * g + rr) * 128
                           + ((64 * hq + 32 * jq + 8 * ss) ^ swz_tr);
                pa[jq][0] = tr8<0>(a);
                pa[jq][1] = tr8<512>(a);
            }
            #pragma unroll
            for (int jc = 0; jc < 8; ++jc) {
                unsigned a = sbase
                           + (32 * kb + 8 * g + rr) * 512
                           + ((256 * hc + 32 * jc + 8 * ss) ^ swz_tr);
                vbf[jc][0] = tr8<0>(a);
                vbf[jc][1] = tr8<2048>(a);
            }
            asm volatile("s_waitcnt lgkmcnt(0)" ::: "memory");
            __builtin_amdgcn_sched_barrier(0);
            #pragma unroll
            for (int jq = 0; jq < 2; ++jq) {
                short8 A = mk8(pa[jq][0], pa[jq][1]);
                #pragma unroll
                for (int jc = 0; jc < 8; ++jc) {
                    short8 Bf = mk8(vbf[jc][0], vbf[jc][1]);
                    acc[jq][jc] = __builtin_amdgcn_mfma_f32_16x16x32_bf16(
                                      A, Bf, acc[jq][jc], 0, 0, 0);
                }
            }
        }
        __syncthreads();   // protect P^T / V before next chunk overwrites
    }

    // --- softmax denominator: reduce across the 16 li-lanes ---
    float rsv[4] = {rs0, rs1, rs2, rs3};
    #pragma unroll
    for (int r = 0; r < 4; ++r) {
        float v = rsv[r];
        v += __shfl_xor(v, 1, 64);
        v += __shfl_xor(v, 2, 64);
        v += __shfl_xor(v, 4, 64);
        v += __shfl_xor(v, 8, 64);
        rsv[r] = v;
    }
    if (li == 0) {
        rsl[16 * w + 4 * g + 0] = rsv[0];
        rsl[16 * w + 4 * g + 1] = rsv[1];
        rsl[16 * w + 4 * g + 2] = rsv[2];
        rsl[16 * w + 4 * g + 3] = rsv[3];
    }
    __syncthreads();

    float inv[2][4];
    #pragma unroll
    for (int jq = 0; jq < 2; ++jq)
        #pragma unroll
        for (int r = 0; r < 4; ++r)
            inv[jq][r] = 1.0f / rsl[32 * hq + 16 * jq + 4 * g + r];

    const float gm = gamma[0];
    #pragma unroll
    for (int jq = 0; jq < 2; ++jq)
        #pragma unroll
        for (int jc = 0; jc < 8; ++jc) {
            const int c = 128 * hc + 16 * jc + li;
            const size_t rowoff = (size_t)(b * C_ + c) * N_
                                + n0 + 32 * hq + 16 * jq + 4 * g;
            float4 xv = *(const float4*)(x + rowoff);
            f32x4 a = acc[jq][jc];
            float4 o;
            o.x = gm * a[0] * inv[jq][0] + xv.x;
            o.y = gm * a[1] * inv[jq][1] + xv.y;
            o.z = gm * a[2] * inv[jq][2] + xv.z;
            o.w = gm * a[3] * inv[jq][3] + xv.w;
            *(float4*)(out + rowoff) = o;
        }
}

// ---------------------------------------------------------------------------
extern "C" void kernel_launch(void* const* d_in, const int* in_sizes, int n_in,
                              void* d_out, int out_size, void* d_ws, size_t ws_size,
                              hipStream_t stream)
{
    const float* x     = (const float*)d_in[0];
    const float* Wq    = (const float*)d_in[1];
    const float* bq    = (const float*)d_in[2];
    const float* Wk    = (const float*)d_in[3];
    const float* bk    = (const float*)d_in[4];
    const float* Wv    = (const float*)d_in[5];
    const float* bv    = (const float*)d_in[6];
    const float* gamma = (const float*)d_in[7];
    float* out = (float*)d_out;

    ushort_t* ws = (ushort_t*)d_ws;
    ushort_t* Qb = ws;                                   // B*N*32 bf16
    ushort_t* Kb = Qb + (size_t)B_ * N_ * CQK_;          // B*N*32 bf16
    ushort_t* Vb = Kb + (size_t)B_ * N_ * CQK_;          // B*N*256 bf16 (swizzled)

    proj_kernel<<<B_ * (N_ / 64), 256, 0, stream>>>(x, Wq, bq, Wk, bk, Wv, bv,
                                                    Qb, Kb, Vb);
    attn_kernel<<<B_ * (N_ / 64), 256, 0, stream>>>(x, Qb, Kb, Vb, gamma, out);
}

// Round 3
// 151.053 us; speedup vs baseline: 14.3724x; 2.3564x over previous
//
#include <hip/hip_runtime.h>

static constexpr int B_   = 8;
static constexpr int C_   = 256;
static constexpr int CQK_ = 32;
static constexpr int N_   = 4096;   // 64*64

typedef __attribute__((ext_vector_type(4))) float f32x4;
typedef __attribute__((ext_vector_type(8))) short short8;
typedef __attribute__((ext_vector_type(2))) unsigned int u32x2;
typedef unsigned short ushort_t;

// round-to-nearest-even fp32 -> bf16
__device__ inline unsigned short f2bf(float f) {
    unsigned u = __float_as_uint(f);
    return (unsigned short)((u + 0x7FFFu + ((u >> 16) & 1u)) >> 16);
}
__device__ inline unsigned packbf(float lo, float hi) {
    return (unsigned)f2bf(lo) | ((unsigned)f2bf(hi) << 16);
}

// row-dependent XOR swizzle of byte offsets (16B granules); involution
__device__ inline int swzbits(int m) {
    return ((m & 3) << 5) | (((m >> 3) & 1) << 4);
}

template <int OFF>
__device__ inline u32x2 tr8(unsigned a) {
    u32x2 d;
    asm volatile("ds_read_b64_tr_b16 %0, %1 offset:%2"
                 : "=v"(d) : "v"(a), "i"(OFF));
    return d;
}

__device__ inline short8 mk8(u32x2 lo, u32x2 hi) {
    union { unsigned u[4]; short8 s; } v;
    v.u[0] = lo.x; v.u[1] = lo.y; v.u[2] = hi.x; v.u[3] = hi.y;
    return v.s;
}

// ---------------------------------------------------------------------------
// prep: concat + convert weights to bf16, biases to f32 array
// grid = 320 blocks, 256 threads
// ---------------------------------------------------------------------------
__global__ __launch_bounds__(256) void prep_kernel(
    const float* __restrict__ Wq, const float* __restrict__ bq,
    const float* __restrict__ Wk, const float* __restrict__ bk,
    const float* __restrict__ Wv, const float* __restrict__ bv,
    ushort_t* __restrict__ Wall, float* __restrict__ ball)
{
    const int r = blockIdx.x;
    const int t = threadIdx.x;
    const float* src;
    float bsrc;
    if (r < 32)      { src = Wq + (size_t)r * C_;        bsrc = bq[r]; }
    else if (r < 64) { src = Wk + (size_t)(r - 32) * C_; bsrc = bk[r - 32]; }
    else             { src = Wv + (size_t)(r - 64) * C_; bsrc = bv[r - 64]; }
    Wall[(size_t)r * C_ + t] = f2bf(src[t]);
    if (t == 0) ball[r] = bsrc;
}

// ---------------------------------------------------------------------------
// Projection via MFMA: x[b,:,n-tile] (staged bf16 [c][n] in LDS, swizzled)
//  A = Wall rows (global bf16), B = xs via ds_read_b64_tr_b16.
// grid = 512 blocks (b = blk&7, XCD-affine), 256 threads (4 waves)
// wave w: oc in [80w, 80w+80); 5 oc-tiles x 4 n-tiles accumulators
// ---------------------------------------------------------------------------
__global__ __launch_bounds__(256) void proj_kernel(
    const float* __restrict__ x,
    const ushort_t* __restrict__ Wall, const float* __restrict__ ball,
    ushort_t* __restrict__ Qb, ushort_t* __restrict__ Kb, ushort_t* __restrict__ Vb)
{
    __shared__ __align__(16) unsigned char xs[C_ * 128];   // 32 KB: [c][64n] bf16
    typedef __attribute__((address_space(3))) unsigned char lds_byte;
    const unsigned sbase = (unsigned)(size_t)(lds_byte*)xs;

    const int b  = blockIdx.x & 7;
    const int n0 = (blockIdx.x >> 3) << 6;
    const int t  = threadIdx.x;

    // ---- stage x[b, c, n0..n0+63] -> xs[c][n] bf16 (swizzled rows) ----
    {
        const int cst = t >> 4;
        const int n4  = (t & 15) << 2;
        const float* xb = x + (size_t)b * C_ * N_ + n0;
        #pragma unroll
        for (int i = 0; i < 16; ++i) {
            const int c = 16 * i + cst;
            float4 v = *(const float4*)(xb + (size_t)c * N_ + n4);
            u32x2 pk;
            pk.x = packbf(v.x, v.y);
            pk.y = packbf(v.z, v.w);
            *(u32x2*)(xs + c * 128 + ((n4 * 2) ^ swzbits(c))) = pk;
        }
    }
    __syncthreads();

    const int l  = t & 63, w = t >> 6;
    const int li = l & 15, g = l >> 4;
    const int rr = li >> 2, ss = l & 3;
    const int swz_tr = (rr << 5) | ((g & 1) << 4);
    const int ocb = 80 * w;

    f32x4 acc[5][4];
    #pragma unroll
    for (int i = 0; i < 5; ++i)
        #pragma unroll
        for (int j = 0; j < 4; ++j) acc[i][j] = (f32x4){0.f, 0.f, 0.f, 0.f};

    #pragma unroll 2
    for (int kg = 0; kg < 8; ++kg) {
        // B-fragments: cols n, k = c (tr-reads, same pattern as attn's V)
        u32x2 pb[4][2];
        #pragma unroll
        for (int jn = 0; jn < 4; ++jn) {
            unsigned a = sbase + (32 * kg + 8 * g + rr) * 128
                       + ((32 * jn + 8 * ss) ^ swz_tr);
            pb[jn][0] = tr8<0>(a);
            pb[jn][1] = tr8<512>(a);    // +4 c-rows
        }
        // A-fragments: W rows oc, k-contiguous (global, L2-resident)
        short8 af[5];
        #pragma unroll
        for (int tm = 0; tm < 5; ++tm)
            af[tm] = *(const short8*)(Wall + (size_t)(ocb + 16 * tm + li) * C_
                                      + 32 * kg + 8 * g);
        asm volatile("s_waitcnt lgkmcnt(0)" ::: "memory");
        __builtin_amdgcn_sched_barrier(0);
        #pragma unroll
        for (int tm = 0; tm < 5; ++tm) {
            #pragma unroll
            for (int jn = 0; jn < 4; ++jn) {
                short8 Bf = mk8(pb[jn][0], pb[jn][1]);
                acc[tm][jn] = __builtin_amdgcn_mfma_f32_16x16x32_bf16(
                                  af[tm], Bf, acc[tm][jn], 0, 0, 0);
            }
        }
    }

    // ---- epilogue: bias add, pack bf16, route to Q/K/V ----
    #pragma unroll
    for (int tm = 0; tm < 5; ++tm) {
        const int oc0 = ocb + 16 * tm + 4 * g;
        float4 bias = *(const float4*)(ball + oc0);
        #pragma unroll
        for (int jn = 0; jn < 4; ++jn) {
            const int n = n0 + 16 * jn + li;
            f32x4 a = acc[tm][jn];
            u32x2 pk;
            pk.x = packbf(a[0] + bias.x, a[1] + bias.y);
            pk.y = packbf(a[2] + bias.z, a[3] + bias.w);
            if (oc0 < 32) {
                *(u32x2*)(Qb + (size_t)(b * N_ + n) * CQK_ + oc0) = pk;
            } else if (oc0 < 64) {
                *(u32x2*)(Kb + (size_t)(b * N_ + n) * CQK_ + (oc0 - 32)) = pk;
            } else {
                char* dst = (char*)Vb + (size_t)(b * N_ + n) * 512
                          + (((oc0 - 64) * 2) ^ swzbits(n));
                *(u32x2*)dst = pk;
            }
        }
    }
}

// ---------------------------------------------------------------------------
// Fused attention: S=QK^T (MFMA), P=exp(S) unnormalized, PV (MFMA via
// tr-reads), denominator accumulated inline, normalized in epilogue.
// grid = 512 (b = blk&7 XCD-affine), 256 threads (4 waves), 64-query tile
// ---------------------------------------------------------------------------
__global__ __launch_bounds__(256) void attn_kernel(
    const float* __restrict__ x,
    const ushort_t* __restrict__ Qb, const ushort_t* __restrict__ Kb,
    const ushort_t* __restrict__ Vb,
    const float* __restrict__ gamma, float* __restrict__ out)
{
    __shared__ __align__(16) unsigned char smem[32768 + 8192 + 256];
    unsigned char* Pl = smem + 32768;
    float* rsl = (float*)(smem + 32768 + 8192);

    typedef __attribute__((address_space(3))) unsigned char lds_byte;
    const unsigned sbase = (unsigned)(size_t)(lds_byte*)smem;

    const int b  = blockIdx.x & 7;
    const int n0 = (blockIdx.x >> 3) << 6;
    const int t  = threadIdx.x;
    const int l  = t & 63, w = t >> 6;
    const int li = l & 15, g = l >> 4;
    const int rr = li >> 2, ss = l & 3;
    const int hq = w & 1,  hc = w >> 1;
    const int swz_tr = (rr << 5) | ((g & 1) << 4);

    short8 qf = *(const short8*)(Qb + (size_t)(b * N_ + n0 + 16 * w + li) * CQK_ + 8 * g);

    f32x4 acc[2][8];
    #pragma unroll
    for (int i = 0; i < 2; ++i)
        #pragma unroll
        for (int j = 0; j < 8; ++j) acc[i][j] = (f32x4){0.f, 0.f, 0.f, 0.f};
    float rs0 = 0.f, rs1 = 0.f, rs2 = 0.f, rs3 = 0.f;

    const ushort_t* Kbb = Kb + (size_t)(b * N_) * CQK_;
    const char* Vgb = (const char*)Vb + (size_t)(b * N_) * 512;
    const f32x4 zf = {0.f, 0.f, 0.f, 0.f};

    for (int m0 = 0; m0 < N_; m0 += 64) {
        short8 kf[4];
        #pragma unroll
        for (int jm = 0; jm < 4; ++jm)
            kf[jm] = *(const short8*)(Kbb + (size_t)(m0 + 16 * jm + li) * CQK_ + 8 * g);

        {
            const char* gsrc = Vgb + (size_t)m0 * 512 + w * 1024 + l * 16;
            #pragma unroll
            for (int i = 0; i < 8; ++i)
                __builtin_amdgcn_global_load_lds(
                    (const __attribute__((address_space(1))) unsigned int*)(gsrc + i * 4096),
                    (__attribute__((address_space(3))) unsigned int*)(smem + w * 1024 + i * 4096),
                    16, 0, 0);
        }

        #pragma unroll
        for (int jm = 0; jm < 4; ++jm) {
            f32x4 s = __builtin_amdgcn_mfma_f32_16x16x32_bf16(qf, kf[jm], zf, 0, 0, 0);
            float p0 = __expf(s[0]), p1 = __expf(s[1]);
            float p2 = __expf(s[2]), p3 = __expf(s[3]);
            rs0 += p0; rs1 += p1; rs2 += p2; rs3 += p3;
            const int m = 16 * jm + li;
            u32x2 pu; pu.x = packbf(p0, p1); pu.y = packbf(p2, p3);
            *(u32x2*)(Pl + m * 128 + ((32 * w + 8 * g) ^ swzbits(m))) = pu;
        }
        __syncthreads();

        #pragma unroll
        for (int kb = 0; kb < 2; ++kb) {
            u32x2 pa[2][2], vbf[8][2];
            #pragma unroll
            for (int jq = 0; jq < 2; ++jq) {
                unsigned a = sbase + 32768u
                           + (32 * kb + 8 * g + rr) * 128
                           + ((64 * hq + 32 * jq + 8 * ss) ^ swz_tr);
                pa[jq][0] = tr8<0>(a);
                pa[jq][1] = tr8<512>(a);
            }
            #pragma unroll
            for (int jc = 0; jc < 8; ++jc) {
                unsigned a = sbase
                           + (32 * kb + 8 * g + rr) * 512
                           + ((256 * hc + 32 * jc + 8 * ss) ^ swz_tr);
                vbf[jc][0] = tr8<0>(a);
                vbf[jc][1] = tr8<2048>(a);
            }
            asm volatile("s_waitcnt lgkmcnt(0)" ::: "memory");
            __builtin_amdgcn_sched_barrier(0);
            #pragma unroll
            for (int jq = 0; jq < 2; ++jq) {
                short8 A = mk8(pa[jq][0], pa[jq][1]);
                #pragma unroll
                for (int jc = 0; jc < 8; ++jc) {
                    short8 Bf = mk8(vbf[jc][0], vbf[jc][1]);
                    acc[jq][jc] = __builtin_amdgcn_mfma_f32_16x16x32_bf16(
                                      A, Bf, acc[jq][jc], 0, 0, 0);
                }
            }
        }
        __syncthreads();
    }

    float rsv[4] = {rs0, rs1, rs2, rs3};
    #pragma unroll
    for (int r = 0; r < 4; ++r) {
        float v = rsv[r];
        v += __shfl_xor(v, 1, 64);
        v += __shfl_xor(v, 2, 64);
        v += __shfl_xor(v, 4, 64);
        v += __shfl_xor(v, 8, 64);
        rsv[r] = v;
    }
    if (li == 0) {
        rsl[16 * w + 4 * g + 0] = rsv[0];
        rsl[16 * w + 4 * g + 1] = rsv[1];
        rsl[16 * w + 4 * g + 2] = rsv[2];
        rsl[16 * w + 4 * g + 3] = rsv[3];
    }
    __syncthreads();

    float inv[2][4];
    #pragma unroll
    for (int jq = 0; jq < 2; ++jq)
        #pragma unroll
        for (int r = 0; r < 4; ++r)
            inv[jq][r] = 1.0f / rsl[32 * hq + 16 * jq + 4 * g + r];

    const float gm = gamma[0];
    #pragma unroll
    for (int jq = 0; jq < 2; ++jq)
        #pragma unroll
        for (int jc = 0; jc < 8; ++jc) {
            const int c = 128 * hc + 16 * jc + li;
            const size_t rowoff = (size_t)(b * C_ + c) * N_
                                + n0 + 32 * hq + 16 * jq + 4 * g;
            float4 xv = *(const float4*)(x + rowoff);
            f32x4 a = acc[jq][jc];
            float4 o;
            o.x = gm * a[0] * inv[jq][0] + xv.x;
            o.y = gm * a[1] * inv[jq][1] + xv.y;
            o.z = gm * a[2] * inv[jq][2] + xv.z;
            o.w = gm * a[3] * inv[jq][3] + xv.w;
            *(float4*)(out + rowoff) = o;
        }
}

// ---------------------------------------------------------------------------
extern "C" void kernel_launch(void* const* d_in, const int* in_sizes, int n_in,
                              void* d_out, int out_size, void* d_ws, size_t ws_size,
                              hipStream_t stream)
{
    const float* x     = (const float*)d_in[0];
    const float* Wq    = (const float*)d_in[1];
    const float* bq    = (const float*)d_in[2];
    const float* Wk    = (const float*)d_in[3];
    const float* bk    = (const float*)d_in[4];
    const float* Wv    = (const float*)d_in[5];
    const float* bv    = (const float*)d_in[6];
    const float* gamma = (const float*)d_in[7];
    float* out = (float*)d_out;

    ushort_t* ws = (ushort_t*)d_ws;
    ushort_t* Qb   = ws;                                  // B*N*32 bf16
    ushort_t* Kb   = Qb + (size_t)B_ * N_ * CQK_;         // B*N*32 bf16
    ushort_t* Vb   = Kb + (size_t)B_ * N_ * CQK_;         // B*N*256 bf16 (swizzled)
    ushort_t* Wall = Vb + (size_t)B_ * N_ * C_;           // 320*256 bf16
    float*    ball = (float*)(Wall + (size_t)320 * C_);   // 320 f32

    prep_kernel<<<320, 256, 0, stream>>>(Wq, bq, Wk, bk, Wv, bv, Wall, ball);
    proj_kernel<<<B_ * (N_ / 64), 256, 0, stream>>>(x, Wall, ball, Qb, Kb, Vb);
    attn_kernel<<<B_ * (N_ / 64), 256, 0, stream>>>(x, Qb, Kb, Vb, gamma, out);
}